// Round 1
// baseline (6807.259 us; speedup 1.0000x reference)
//
#include <hip/hip_runtime.h>
#include <math.h>

#define N_USERS   50000
#define N_ENTITIES 100000
#define N_NODES   150000
#define N_EDGES   3000000
#define BATCH     8192
#define SLOPE     0.2f
#define EPSF      1e-12f

// ---------------------------------------------------------------------------
// Scatter: side[h] += A[e] * ego_in[t]   (segment_sum of messages)
// D/4 threads per edge, float4 gather, 4 scalar fp32 atomicAdds.
// CONCAT: layer-0 reads the virtual concat(user_embed, entity_embed).
// ---------------------------------------------------------------------------
template<int D, bool CONCAT>
__global__ __launch_bounds__(256)
void scatter_k(const int* __restrict__ all_h, const int* __restrict__ all_t,
               const float* __restrict__ A,
               const float* __restrict__ ego,
               const float* __restrict__ user_emb,
               const float* __restrict__ ent_emb,
               float* __restrict__ side) {
    constexpr int CH = D / 4;                       // float4 chunks per row
    int idx = blockIdx.x * 256 + threadIdx.x;       // N_EDGES*CH <= 48M, fits int
    if (idx >= N_EDGES * CH) return;
    int e = idx / CH;
    int c = idx % CH;
    int t = all_t[e];
    int h = all_h[e];
    float a = A[e];
    const float* srow;
    if (CONCAT) {
        srow = (t < N_USERS) ? (user_emb + (size_t)t * 64)
                             : (ent_emb + (size_t)(t - N_USERS) * 64);
    } else {
        srow = ego + (size_t)t * D;
    }
    float4 v = ((const float4*)srow)[c];
    float* dst = side + (size_t)h * D + c * 4;
    atomicAdd(dst + 0, a * v.x);
    atomicAdd(dst + 1, a * v.y);
    atomicAdd(dst + 2, a * v.z);
    atomicAdd(dst + 3, a * v.w);
}

// ---------------------------------------------------------------------------
// Transform: ego_out = leaky((ego+side)@Wgc + bgc) + leaky((ego*side)@Wbi + bbi)
// One wave per node row; weights staged in LDS; 4 rows per 256-thread block.
// ---------------------------------------------------------------------------
template<int DIN, int DOUT, bool CONCAT>
__global__ __launch_bounds__(256)
void transform_k(const float* __restrict__ ego_in,
                 const float* __restrict__ user_emb,
                 const float* __restrict__ ent_emb,
                 const float* __restrict__ side,
                 const float* __restrict__ Wgc, const float* __restrict__ bgc,
                 const float* __restrict__ Wbi, const float* __restrict__ bbi,
                 float* __restrict__ ego_out) {
    __shared__ float sWgc[DIN * DOUT], sWbi[DIN * DOUT];
    __shared__ float sbgc[DOUT], sbbi[DOUT];
    __shared__ float su[4][DIN], sv[4][DIN];

    for (int i = threadIdx.x; i < DIN * DOUT; i += 256) {
        sWgc[i] = Wgc[i];
        sWbi[i] = Wbi[i];
    }
    if (threadIdx.x < DOUT) {
        sbgc[threadIdx.x] = bgc[threadIdx.x];
        sbbi[threadIdx.x] = bbi[threadIdx.x];
    }

    int w = threadIdx.x >> 6;
    int lane = threadIdx.x & 63;
    int row = blockIdx.x * 4 + w;
    bool valid = row < N_NODES;

    if (valid && lane < DIN) {
        float e;
        if (CONCAT) {
            e = (row < N_USERS) ? user_emb[(size_t)row * 64 + lane]
                                : ent_emb[(size_t)(row - N_USERS) * 64 + lane];
        } else {
            e = ego_in[(size_t)row * DIN + lane];
        }
        float s = side[(size_t)row * DIN + lane];
        su[w][lane] = e + s;
        sv[w][lane] = e * s;
    }
    __syncthreads();

    if (valid && lane < DOUT) {
        float ag = sbgc[lane];
        float ab = sbbi[lane];
        #pragma unroll
        for (int i = 0; i < DIN; ++i) {
            ag += su[w][i] * sWgc[i * DOUT + lane];
            ab += sv[w][i] * sWbi[i * DOUT + lane];
        }
        ag = ag > 0.f ? ag : SLOPE * ag;
        ab = ab > 0.f ? ab : SLOPE * ab;
        ego_out[(size_t)row * DOUT + lane] = ag + ab;
    }
}

// ---------------------------------------------------------------------------
// Gather: out rows = [ego0(64) | norm(ego1)(64) | norm(ego2)(32) | norm(ego3)(16)]
// One wave per output row; L2 norms via 64-lane shuffle reduction.
// ---------------------------------------------------------------------------
__global__ __launch_bounds__(64)
void gather_k(const int* __restrict__ users, const int* __restrict__ pos,
              const int* __restrict__ neg,
              const float* __restrict__ user_emb, const float* __restrict__ ent_emb,
              const float* __restrict__ ego1, const float* __restrict__ ego2,
              const float* __restrict__ ego3,
              float* __restrict__ out) {
    int r = blockIdx.x;               // 0 .. 3*BATCH-1
    int lane = threadIdx.x;           // 0 .. 63
    int which = r / BATCH;
    int i = r - which * BATCH;
    int node;
    if (which == 0)      node = users[i];
    else if (which == 1) node = N_USERS + pos[i];
    else                 node = N_USERS + neg[i];

    float* o = out + (size_t)r * 176;

    // section 0: raw ego0
    float x0 = (node < N_USERS) ? user_emb[(size_t)node * 64 + lane]
                                : ent_emb[(size_t)(node - N_USERS) * 64 + lane];
    o[lane] = x0;

    // section 1: normalized ego1 (64)
    float x1 = ego1[(size_t)node * 64 + lane];
    float ss = x1 * x1;
    #pragma unroll
    for (int off = 32; off > 0; off >>= 1) ss += __shfl_xor(ss, off, 64);
    o[64 + lane] = x1 / fmaxf(sqrtf(ss), EPSF);

    // section 2: normalized ego2 (32)
    float x2 = (lane < 32) ? ego2[(size_t)node * 32 + lane] : 0.f;
    float ss2 = x2 * x2;
    #pragma unroll
    for (int off = 32; off > 0; off >>= 1) ss2 += __shfl_xor(ss2, off, 64);
    if (lane < 32) o[128 + lane] = x2 / fmaxf(sqrtf(ss2), EPSF);

    // section 3: normalized ego3 (16)
    float x3 = (lane < 16) ? ego3[(size_t)node * 16 + lane] : 0.f;
    float ss3 = x3 * x3;
    #pragma unroll
    for (int off = 32; off > 0; off >>= 1) ss3 += __shfl_xor(ss3, off, 64);
    if (lane < 16) o[160 + lane] = x3 / fmaxf(sqrtf(ss3), EPSF);
}

// ---------------------------------------------------------------------------
extern "C" void kernel_launch(void* const* d_in, const int* in_sizes, int n_in,
                              void* d_out, int out_size, void* d_ws, size_t ws_size,
                              hipStream_t stream) {
    const int*   users    = (const int*)d_in[0];
    const int*   pos      = (const int*)d_in[1];
    const int*   neg      = (const int*)d_in[2];
    const int*   all_h    = (const int*)d_in[3];
    const int*   all_t    = (const int*)d_in[4];
    const float* A        = (const float*)d_in[5];
    const float* user_emb = (const float*)d_in[6];
    const float* ent_emb  = (const float*)d_in[7];
    const float* Wgc0 = (const float*)d_in[8];
    const float* bgc0 = (const float*)d_in[9];
    const float* Wbi0 = (const float*)d_in[10];
    const float* bbi0 = (const float*)d_in[11];
    const float* Wgc1 = (const float*)d_in[12];
    const float* bgc1 = (const float*)d_in[13];
    const float* Wbi1 = (const float*)d_in[14];
    const float* bbi1 = (const float*)d_in[15];
    const float* Wgc2 = (const float*)d_in[16];
    const float* bgc2 = (const float*)d_in[17];
    const float* Wbi2 = (const float*)d_in[18];
    const float* bbi2 = (const float*)d_in[19];

    float* ws   = (float*)d_ws;
    float* side = ws;                          // 150000*64 = 9.6M floats (reused)
    float* ego1 = ws + 9600000;                // 150000*64
    float* ego2 = ws + 19200000;               // 150000*32
    float* ego3 = ws + 24000000;               // 150000*16
    float* out  = (float*)d_out;

    const int nTransBlocks = (N_NODES + 3) / 4;

    // ---- layer 0 (DIN=64 -> DOUT=64), ego_in = concat(user_emb, ent_emb)
    hipMemsetAsync(side, 0, (size_t)N_NODES * 64 * sizeof(float), stream);
    {
        int total = N_EDGES * 16;
        scatter_k<64, true><<<(total + 255) / 256, 256, 0, stream>>>(
            all_h, all_t, A, nullptr, user_emb, ent_emb, side);
        transform_k<64, 64, true><<<nTransBlocks, 256, 0, stream>>>(
            nullptr, user_emb, ent_emb, side, Wgc0, bgc0, Wbi0, bbi0, ego1);
    }

    // ---- layer 1 (64 -> 32), ego_in = ego1
    hipMemsetAsync(side, 0, (size_t)N_NODES * 64 * sizeof(float), stream);
    {
        int total = N_EDGES * 16;
        scatter_k<64, false><<<(total + 255) / 256, 256, 0, stream>>>(
            all_h, all_t, A, ego1, nullptr, nullptr, side);
        transform_k<64, 32, false><<<nTransBlocks, 256, 0, stream>>>(
            ego1, nullptr, nullptr, side, Wgc1, bgc1, Wbi1, bbi1, ego2);
    }

    // ---- layer 2 (32 -> 16), ego_in = ego2
    hipMemsetAsync(side, 0, (size_t)N_NODES * 32 * sizeof(float), stream);
    {
        int total = N_EDGES * 8;
        scatter_k<32, false><<<(total + 255) / 256, 256, 0, stream>>>(
            all_h, all_t, A, ego2, nullptr, nullptr, side);
        transform_k<32, 16, false><<<nTransBlocks, 256, 0, stream>>>(
            ego2, nullptr, nullptr, side, Wgc2, bgc2, Wbi2, bbi2, ego3);
    }

    // ---- final gather + lazy normalization
    gather_k<<<3 * BATCH, 64, 0, stream>>>(
        users, pos, neg, user_emb, ent_emb, ego1, ego2, ego3, out);
}

// Round 3
// 1827.883 us; speedup vs baseline: 3.7241x; 3.7241x over previous
//
#include <hip/hip_runtime.h>
#include <math.h>

#define N_USERS    50000
#define N_ENTITIES 100000
#define N_NODES    150000
#define N_EDGES    3000000
#define BATCH      8192
#define SLOPE      0.2f
#define EPSF       1e-12f

// ---------------------------------------------------------------------------
// CSR build: histogram -> exclusive scan -> fill (sorted-by-h edge list).
// all_h is shared by all 3 layers, so this is built once per call.
// ---------------------------------------------------------------------------
__global__ __launch_bounds__(256)
void hist_k(const int* __restrict__ all_h, int* __restrict__ cnt) {
    int e = blockIdx.x * 256 + threadIdx.x;
    if (e < N_EDGES) atomicAdd(&cnt[all_h[e]], 1);
}

// single-block exclusive scan of cnt[0..N_NODES) -> offsets, offsets[N_NODES]=total
__global__ __launch_bounds__(256)
void scan_k(const int* __restrict__ cnt, int* __restrict__ offsets) {
    constexpr int CHUNK = (N_NODES + 255) / 256;   // 586
    __shared__ int partial[256];
    __shared__ int excl[256];
    int tid = threadIdx.x;
    int begin = tid * CHUNK;
    int end = begin + CHUNK; if (end > N_NODES) end = N_NODES;
    int s = 0;
    for (int i = begin; i < end; ++i) s += cnt[i];
    partial[tid] = s;
    __syncthreads();
    if (tid == 0) {
        int run = 0;
        for (int i = 0; i < 256; ++i) { excl[i] = run; run += partial[i]; }
    }
    __syncthreads();
    int run = excl[tid];
    for (int i = begin; i < end; ++i) { offsets[i] = run; run += cnt[i]; }
    if (end == N_NODES && begin < N_NODES) offsets[N_NODES] = run;
}

__global__ __launch_bounds__(256)
void fill_k(const int* __restrict__ all_h, const int* __restrict__ all_t,
            const float* __restrict__ A,
            const int* __restrict__ offsets, int* __restrict__ cursor,
            int* __restrict__ edge_t, float* __restrict__ edge_a) {
    int e = blockIdx.x * 256 + threadIdx.x;
    if (e >= N_EDGES) return;
    int h = all_h[e];
    int p = offsets[h] + atomicAdd(&cursor[h], 1);
    edge_t[p] = all_t[e];
    edge_a[p] = A[e];
}

// ---------------------------------------------------------------------------
// Fused layer: per node h (one wave each):
//   side = sum_e A_e * ego[t_e]          (no atomics, CSR edge list)
//   ego_out = leaky((ego+side)@Wgc+bgc) + leaky((ego*side)@Wbi+bbi)
// Block = 256 = 4 waves = 4 nodes. Weights staged in LDS.
// Grid exactly N_NODES/4 blocks (150000 % 4 == 0, no partial block).
// ---------------------------------------------------------------------------
template<int DIN, int DOUT, bool CONCAT>
__global__ __launch_bounds__(256)
void layer_k(const int* __restrict__ offsets,
             const int* __restrict__ edge_t, const float* __restrict__ edge_a,
             const float* __restrict__ ego_in,
             const float* __restrict__ user_emb, const float* __restrict__ ent_emb,
             const float* __restrict__ Wgc, const float* __restrict__ bgc,
             const float* __restrict__ Wbi, const float* __restrict__ bbi,
             float* __restrict__ ego_out) {
    __shared__ float sWgc[DIN * DOUT], sWbi[DIN * DOUT];
    __shared__ float sbgc[DOUT], sbbi[DOUT];
    __shared__ float su[4][DIN], sv[4][DIN];

    for (int i = threadIdx.x; i < DIN * DOUT; i += 256) {
        sWgc[i] = Wgc[i];
        sWbi[i] = Wbi[i];
    }
    if (threadIdx.x < DOUT) {
        sbgc[threadIdx.x] = bgc[threadIdx.x];
        sbbi[threadIdx.x] = bbi[threadIdx.x];
    }
    __syncthreads();

    int w = threadIdx.x >> 6;
    int lane = threadIdx.x & 63;
    int h = blockIdx.x * 4 + w;

    int e0 = offsets[h], e1 = offsets[h + 1];

    if (DIN == 64) {
        float acc = 0.f;
        for (int e = e0; e < e1; ++e) {
            int t = edge_t[e];
            float a = edge_a[e];
            const float* row;
            if (CONCAT) {
                row = (t < N_USERS) ? (user_emb + (size_t)t * 64)
                                    : (ent_emb + (size_t)(t - N_USERS) * 64);
            } else {
                row = ego_in + (size_t)t * 64;
            }
            acc += a * row[lane];
        }
        float es;
        if (CONCAT) {
            es = (h < N_USERS) ? user_emb[(size_t)h * 64 + lane]
                               : ent_emb[(size_t)(h - N_USERS) * 64 + lane];
        } else {
            es = ego_in[(size_t)h * 64 + lane];
        }
        su[w][lane] = es + acc;
        sv[w][lane] = es * acc;
    } else {  // DIN == 32: lanes split even/odd edges, combine via shfl
        int col = lane & 31;
        int half = lane >> 5;
        float acc = 0.f;
        for (int e = e0 + half; e < e1; e += 2) {
            int t = edge_t[e];
            float a = edge_a[e];
            acc += a * ego_in[(size_t)t * 32 + col];
        }
        acc += __shfl_xor(acc, 32, 64);
        if (lane < 32) {
            float es = ego_in[(size_t)h * 32 + lane];
            su[w][lane] = es + acc;
            sv[w][lane] = es * acc;
        }
    }
    __syncthreads();

    if (lane < DOUT) {
        float ag = sbgc[lane];
        float ab = sbbi[lane];
        #pragma unroll
        for (int i = 0; i < DIN; ++i) {
            ag += su[w][i] * sWgc[i * DOUT + lane];
            ab += sv[w][i] * sWbi[i * DOUT + lane];
        }
        ag = ag > 0.f ? ag : SLOPE * ag;
        ab = ab > 0.f ? ab : SLOPE * ab;
        ego_out[(size_t)h * DOUT + lane] = ag + ab;
    }
}

// ---------------------------------------------------------------------------
// Gather: out rows = [ego0(64) | norm(ego1)(64) | norm(ego2)(32) | norm(ego3)(16)]
// ---------------------------------------------------------------------------
__global__ __launch_bounds__(64)
void gather_k(const int* __restrict__ users, const int* __restrict__ pos,
              const int* __restrict__ neg,
              const float* __restrict__ user_emb, const float* __restrict__ ent_emb,
              const float* __restrict__ ego1, const float* __restrict__ ego2,
              const float* __restrict__ ego3,
              float* __restrict__ out) {
    int r = blockIdx.x;               // 0 .. 3*BATCH-1
    int lane = threadIdx.x;           // 0 .. 63
    int which = r / BATCH;
    int i = r - which * BATCH;
    int node;
    if (which == 0)      node = users[i];
    else if (which == 1) node = N_USERS + pos[i];
    else                 node = N_USERS + neg[i];

    float* o = out + (size_t)r * 176;

    float x0 = (node < N_USERS) ? user_emb[(size_t)node * 64 + lane]
                                : ent_emb[(size_t)(node - N_USERS) * 64 + lane];
    o[lane] = x0;

    float x1 = ego1[(size_t)node * 64 + lane];
    float ss = x1 * x1;
    #pragma unroll
    for (int off = 32; off > 0; off >>= 1) ss += __shfl_xor(ss, off, 64);
    o[64 + lane] = x1 / fmaxf(sqrtf(ss), EPSF);

    float x2 = (lane < 32) ? ego2[(size_t)node * 32 + lane] : 0.f;
    float ss2 = x2 * x2;
    #pragma unroll
    for (int off = 32; off > 0; off >>= 1) ss2 += __shfl_xor(ss2, off, 64);
    if (lane < 32) o[128 + lane] = x2 / fmaxf(sqrtf(ss2), EPSF);

    float x3 = (lane < 16) ? ego3[(size_t)node * 16 + lane] : 0.f;
    float ss3 = x3 * x3;
    #pragma unroll
    for (int off = 32; off > 0; off >>= 1) ss3 += __shfl_xor(ss3, off, 64);
    if (lane < 16) o[160 + lane] = x3 / fmaxf(sqrtf(ss3), EPSF);
}

// ---------------------------------------------------------------------------
extern "C" void kernel_launch(void* const* d_in, const int* in_sizes, int n_in,
                              void* d_out, int out_size, void* d_ws, size_t ws_size,
                              hipStream_t stream) {
    const int*   users    = (const int*)d_in[0];
    const int*   pos      = (const int*)d_in[1];
    const int*   neg      = (const int*)d_in[2];
    const int*   all_h    = (const int*)d_in[3];
    const int*   all_t    = (const int*)d_in[4];
    const float* A        = (const float*)d_in[5];
    const float* user_emb = (const float*)d_in[6];
    const float* ent_emb  = (const float*)d_in[7];
    const float* Wgc0 = (const float*)d_in[8];
    const float* bgc0 = (const float*)d_in[9];
    const float* Wbi0 = (const float*)d_in[10];
    const float* bbi0 = (const float*)d_in[11];
    const float* Wgc1 = (const float*)d_in[12];
    const float* bgc1 = (const float*)d_in[13];
    const float* Wbi1 = (const float*)d_in[14];
    const float* bbi1 = (const float*)d_in[15];
    const float* Wgc2 = (const float*)d_in[16];
    const float* bgc2 = (const float*)d_in[17];
    const float* Wbi2 = (const float*)d_in[18];
    const float* bbi2 = (const float*)d_in[19];

    // ---- workspace carve-up (256B-aligned chunks) ----
    char* p = (char*)d_ws;
    int*   cnt     = (int*)p;    p += ((size_t)N_NODES * 4 + 255) & ~255ull;       // counts, then reused as cursor
    int*   offsets = (int*)p;    p += ((size_t)(N_NODES + 1) * 4 + 255) & ~255ull;
    int*   edge_t  = (int*)p;    p += ((size_t)N_EDGES * 4 + 255) & ~255ull;
    float* edge_a  = (float*)p;  p += ((size_t)N_EDGES * 4 + 255) & ~255ull;
    float* ego1    = (float*)p;  p += ((size_t)N_NODES * 64 * 4 + 255) & ~255ull;
    float* ego2    = (float*)p;  p += ((size_t)N_NODES * 32 * 4 + 255) & ~255ull;
    float* ego3    = (float*)p;  p += ((size_t)N_NODES * 16 * 4 + 255) & ~255ull;
    float* out     = (float*)d_out;

    const int edgeBlocks = (N_EDGES + 255) / 256;
    const int nodeBlocks = N_NODES / 4;   // 150000 % 4 == 0

    // ---- CSR build (once; all_h shared across layers) ----
    (void)hipMemsetAsync(cnt, 0, (size_t)N_NODES * 4, stream);
    hist_k<<<edgeBlocks, 256, 0, stream>>>(all_h, cnt);
    scan_k<<<1, 256, 0, stream>>>(cnt, offsets);
    (void)hipMemsetAsync(cnt, 0, (size_t)N_NODES * 4, stream);   // now cursor
    fill_k<<<edgeBlocks, 256, 0, stream>>>(all_h, all_t, A, offsets, cnt, edge_t, edge_a);

    // ---- fused layers ----
    layer_k<64, 64, true><<<nodeBlocks, 256, 0, stream>>>(
        offsets, edge_t, edge_a, nullptr, user_emb, ent_emb,
        Wgc0, bgc0, Wbi0, bbi0, ego1);
    layer_k<64, 32, false><<<nodeBlocks, 256, 0, stream>>>(
        offsets, edge_t, edge_a, ego1, nullptr, nullptr,
        Wgc1, bgc1, Wbi1, bbi1, ego2);
    layer_k<32, 16, false><<<nodeBlocks, 256, 0, stream>>>(
        offsets, edge_t, edge_a, ego2, nullptr, nullptr,
        Wgc2, bgc2, Wbi2, bbi2, ego3);

    // ---- final gather + lazy normalization ----
    gather_k<<<3 * BATCH, 64, 0, stream>>>(
        users, pos, neg, user_emb, ent_emb, ego1, ego2, ego3, out);
}

// Round 4
// 1244.489 us; speedup vs baseline: 5.4699x; 1.4688x over previous
//
#include <hip/hip_runtime.h>
#include <math.h>

#define N_USERS    50000
#define N_ENTITIES 100000
#define N_NODES    150000
#define N_EDGES    3000000
#define BATCH      8192
#define SLOPE      0.2f
#define EPSF       1e-12f

// ---------------------------------------------------------------------------
// CSR build: histogram -> exclusive scan -> fill (sorted-by-h edge records).
// all_h is shared by all 3 layers, so this is built once per call.
// Edge record: int2 { t, bitcast(a) } -> one 8B uniform load per edge.
// ---------------------------------------------------------------------------
__global__ __launch_bounds__(256)
void hist_k(const int* __restrict__ all_h, int* __restrict__ cnt) {
    int e = blockIdx.x * 256 + threadIdx.x;
    if (e < N_EDGES) atomicAdd(&cnt[all_h[e]], 1);
}

__global__ __launch_bounds__(256)
void scan_k(const int* __restrict__ cnt, int* __restrict__ offsets) {
    constexpr int CHUNK = (N_NODES + 255) / 256;   // 586
    __shared__ int partial[256];
    __shared__ int excl[256];
    int tid = threadIdx.x;
    int begin = tid * CHUNK;
    int end = begin + CHUNK; if (end > N_NODES) end = N_NODES;
    int s = 0;
    for (int i = begin; i < end; ++i) s += cnt[i];
    partial[tid] = s;
    __syncthreads();
    if (tid == 0) {
        int run = 0;
        for (int i = 0; i < 256; ++i) { excl[i] = run; run += partial[i]; }
    }
    __syncthreads();
    int run = excl[tid];
    for (int i = begin; i < end; ++i) { offsets[i] = run; run += cnt[i]; }
    if (end == N_NODES && begin < N_NODES) offsets[N_NODES] = run;
}

__global__ __launch_bounds__(256)
void fill_k(const int* __restrict__ all_h, const int* __restrict__ all_t,
            const float* __restrict__ A,
            const int* __restrict__ offsets, int* __restrict__ cursor,
            int2* __restrict__ edge_ta) {
    int e = blockIdx.x * 256 + threadIdx.x;
    if (e >= N_EDGES) return;
    int h = all_h[e];
    int p = offsets[h] + atomicAdd(&cursor[h], 1);
    edge_ta[p] = make_int2(all_t[e], __float_as_int(A[e]));
}

// ---------------------------------------------------------------------------
// Fused layer: one wave per node h:
//   side = sum_e A_e * ego[t_e]          (CSR, no atomics, 4x unrolled MLP)
//   ego_out = leaky((ego+side)@Wgc+bgc) + leaky((ego*side)@Wbi+bbi)
// No weight staging (each W element is read exactly once per block either
// way; LDS staging only cost occupancy). No __syncthreads: su/sv are
// per-wave-private LDS rows.
// ---------------------------------------------------------------------------
template<int DIN, int DOUT, bool CONCAT>
__global__ __launch_bounds__(256)
void layer_k(const int* __restrict__ offsets,
             const int2* __restrict__ edge_ta,
             const float* __restrict__ ego_in,
             const float* __restrict__ user_emb, const float* __restrict__ ent_emb,
             const float* __restrict__ Wgc, const float* __restrict__ bgc,
             const float* __restrict__ Wbi, const float* __restrict__ bbi,
             float* __restrict__ ego_out) {
    __shared__ float su[4][DIN], sv[4][DIN];

    int w = threadIdx.x >> 6;
    int lane = threadIdx.x & 63;
    int h = blockIdx.x * 4 + w;

    int e0 = offsets[h], e1 = offsets[h + 1];

    if (DIN == 64) {
        float acc = 0.f;
        int e = e0;
        #define ROW64(t) (CONCAT ? (((t) < N_USERS) ? (user_emb + (size_t)(t) * 64) \
                                                    : (ent_emb + (size_t)((t) - N_USERS) * 64)) \
                                 : (ego_in + (size_t)(t) * 64))
        for (; e + 4 <= e1; e += 4) {
            int2 p0 = edge_ta[e + 0];
            int2 p1 = edge_ta[e + 1];
            int2 p2 = edge_ta[e + 2];
            int2 p3 = edge_ta[e + 3];
            const float* r0 = ROW64(p0.x);
            const float* r1 = ROW64(p1.x);
            const float* r2 = ROW64(p2.x);
            const float* r3 = ROW64(p3.x);
            float x0 = r0[lane], x1 = r1[lane], x2 = r2[lane], x3 = r3[lane];
            acc = fmaf(__int_as_float(p0.y), x0, acc);
            acc = fmaf(__int_as_float(p1.y), x1, acc);
            acc = fmaf(__int_as_float(p2.y), x2, acc);
            acc = fmaf(__int_as_float(p3.y), x3, acc);
        }
        for (; e < e1; ++e) {
            int2 p = edge_ta[e];
            acc = fmaf(__int_as_float(p.y), ROW64(p.x)[lane], acc);
        }
        #undef ROW64
        float es;
        if (CONCAT) {
            es = (h < N_USERS) ? user_emb[(size_t)h * 64 + lane]
                               : ent_emb[(size_t)(h - N_USERS) * 64 + lane];
        } else {
            es = ego_in[(size_t)h * 64 + lane];
        }
        su[w][lane] = es + acc;
        sv[w][lane] = es * acc;
    } else {  // DIN == 32: two half-waves split the edges, combine via shfl
        int col = lane & 31;
        int half = lane >> 5;
        float acc = 0.f;
        int e = e0 + half;
        for (; e + 6 < e1; e += 8) {
            int2 p0 = edge_ta[e + 0];
            int2 p1 = edge_ta[e + 2];
            int2 p2 = edge_ta[e + 4];
            int2 p3 = edge_ta[e + 6];
            float x0 = ego_in[(size_t)p0.x * 32 + col];
            float x1 = ego_in[(size_t)p1.x * 32 + col];
            float x2 = ego_in[(size_t)p2.x * 32 + col];
            float x3 = ego_in[(size_t)p3.x * 32 + col];
            acc = fmaf(__int_as_float(p0.y), x0, acc);
            acc = fmaf(__int_as_float(p1.y), x1, acc);
            acc = fmaf(__int_as_float(p2.y), x2, acc);
            acc = fmaf(__int_as_float(p3.y), x3, acc);
        }
        for (; e < e1; e += 2) {
            int2 p = edge_ta[e];
            acc = fmaf(__int_as_float(p.y), ego_in[(size_t)p.x * 32 + col], acc);
        }
        acc += __shfl_xor(acc, 32, 64);
        if (lane < 32) {
            float es = ego_in[(size_t)h * 32 + lane];
            su[w][lane] = es + acc;
            sv[w][lane] = es * acc;
        }
    }
    // no __syncthreads needed: su[w]/sv[w] are wave-private

    if (lane < DOUT) {
        float ag = bgc[lane];
        float ab = bbi[lane];
        #pragma unroll 8
        for (int i = 0; i < DIN; ++i) {
            float uu = su[w][i];
            float vv = sv[w][i];
            ag = fmaf(uu, Wgc[i * DOUT + lane], ag);
            ab = fmaf(vv, Wbi[i * DOUT + lane], ab);
        }
        ag = ag > 0.f ? ag : SLOPE * ag;
        ab = ab > 0.f ? ab : SLOPE * ab;
        ego_out[(size_t)h * DOUT + lane] = ag + ab;
    }
}

// ---------------------------------------------------------------------------
// Gather: out rows = [ego0(64) | norm(ego1)(64) | norm(ego2)(32) | norm(ego3)(16)]
// ---------------------------------------------------------------------------
__global__ __launch_bounds__(64)
void gather_k(const int* __restrict__ users, const int* __restrict__ pos,
              const int* __restrict__ neg,
              const float* __restrict__ user_emb, const float* __restrict__ ent_emb,
              const float* __restrict__ ego1, const float* __restrict__ ego2,
              const float* __restrict__ ego3,
              float* __restrict__ out) {
    int r = blockIdx.x;               // 0 .. 3*BATCH-1
    int lane = threadIdx.x;           // 0 .. 63
    int which = r / BATCH;
    int i = r - which * BATCH;
    int node;
    if (which == 0)      node = users[i];
    else if (which == 1) node = N_USERS + pos[i];
    else                 node = N_USERS + neg[i];

    float* o = out + (size_t)r * 176;

    float x0 = (node < N_USERS) ? user_emb[(size_t)node * 64 + lane]
                                : ent_emb[(size_t)(node - N_USERS) * 64 + lane];
    o[lane] = x0;

    float x1 = ego1[(size_t)node * 64 + lane];
    float ss = x1 * x1;
    #pragma unroll
    for (int off = 32; off > 0; off >>= 1) ss += __shfl_xor(ss, off, 64);
    o[64 + lane] = x1 / fmaxf(sqrtf(ss), EPSF);

    float x2 = (lane < 32) ? ego2[(size_t)node * 32 + lane] : 0.f;
    float ss2 = x2 * x2;
    #pragma unroll
    for (int off = 32; off > 0; off >>= 1) ss2 += __shfl_xor(ss2, off, 64);
    if (lane < 32) o[128 + lane] = x2 / fmaxf(sqrtf(ss2), EPSF);

    float x3 = (lane < 16) ? ego3[(size_t)node * 16 + lane] : 0.f;
    float ss3 = x3 * x3;
    #pragma unroll
    for (int off = 32; off > 0; off >>= 1) ss3 += __shfl_xor(ss3, off, 64);
    if (lane < 16) o[160 + lane] = x3 / fmaxf(sqrtf(ss3), EPSF);
}

// ---------------------------------------------------------------------------
extern "C" void kernel_launch(void* const* d_in, const int* in_sizes, int n_in,
                              void* d_out, int out_size, void* d_ws, size_t ws_size,
                              hipStream_t stream) {
    const int*   users    = (const int*)d_in[0];
    const int*   pos      = (const int*)d_in[1];
    const int*   neg      = (const int*)d_in[2];
    const int*   all_h    = (const int*)d_in[3];
    const int*   all_t    = (const int*)d_in[4];
    const float* A        = (const float*)d_in[5];
    const float* user_emb = (const float*)d_in[6];
    const float* ent_emb  = (const float*)d_in[7];
    const float* Wgc0 = (const float*)d_in[8];
    const float* bgc0 = (const float*)d_in[9];
    const float* Wbi0 = (const float*)d_in[10];
    const float* bbi0 = (const float*)d_in[11];
    const float* Wgc1 = (const float*)d_in[12];
    const float* bgc1 = (const float*)d_in[13];
    const float* Wbi1 = (const float*)d_in[14];
    const float* bbi1 = (const float*)d_in[15];
    const float* Wgc2 = (const float*)d_in[16];
    const float* bgc2 = (const float*)d_in[17];
    const float* Wbi2 = (const float*)d_in[18];
    const float* bbi2 = (const float*)d_in[19];

    // ---- workspace carve-up (256B-aligned chunks) ----
    char* p = (char*)d_ws;
    int*   cnt     = (int*)p;    p += ((size_t)N_NODES * 4 + 255) & ~255ull;   // counts, then cursor
    int*   offsets = (int*)p;    p += ((size_t)(N_NODES + 1) * 4 + 255) & ~255ull;
    int2*  edge_ta = (int2*)p;   p += ((size_t)N_EDGES * 8 + 255) & ~255ull;
    float* ego1    = (float*)p;  p += ((size_t)N_NODES * 64 * 4 + 255) & ~255ull;
    float* ego2    = (float*)p;  p += ((size_t)N_NODES * 32 * 4 + 255) & ~255ull;
    float* ego3    = (float*)p;  p += ((size_t)N_NODES * 16 * 4 + 255) & ~255ull;
    float* out     = (float*)d_out;

    const int edgeBlocks = (N_EDGES + 255) / 256;
    const int nodeBlocks = N_NODES / 4;   // 150000 % 4 == 0

    // ---- CSR build (once; all_h shared across layers) ----
    (void)hipMemsetAsync(cnt, 0, (size_t)N_NODES * 4, stream);
    hist_k<<<edgeBlocks, 256, 0, stream>>>(all_h, cnt);
    scan_k<<<1, 256, 0, stream>>>(cnt, offsets);
    (void)hipMemsetAsync(cnt, 0, (size_t)N_NODES * 4, stream);   // now cursor
    fill_k<<<edgeBlocks, 256, 0, stream>>>(all_h, all_t, A, offsets, cnt, edge_ta);

    // ---- fused layers ----
    layer_k<64, 64, true><<<nodeBlocks, 256, 0, stream>>>(
        offsets, edge_ta, nullptr, user_emb, ent_emb,
        Wgc0, bgc0, Wbi0, bbi0, ego1);
    layer_k<64, 32, false><<<nodeBlocks, 256, 0, stream>>>(
        offsets, edge_ta, ego1, nullptr, nullptr,
        Wgc1, bgc1, Wbi1, bbi1, ego2);
    layer_k<32, 16, false><<<nodeBlocks, 256, 0, stream>>>(
        offsets, edge_ta, ego2, nullptr, nullptr,
        Wgc2, bgc2, Wbi2, bbi2, ego3);

    // ---- final gather + lazy normalization ----
    gather_k<<<3 * BATCH, 64, 0, stream>>>(
        users, pos, neg, user_emb, ent_emb, ego1, ego2, ego3, out);
}

// Round 5
// 1084.667 us; speedup vs baseline: 6.2759x; 1.1473x over previous
//
#include <hip/hip_runtime.h>
#include <math.h>

#define N_USERS    50000
#define N_ENTITIES 100000
#define N_NODES    150000
#define N_EDGES    3000000
#define BATCH      8192
#define SLOPE      0.2f
#define EPSF       1e-12f

// ---------------------------------------------------------------------------
// CSR build: histogram -> exclusive scan -> fill (sorted-by-h edge records).
// Edge record: int2 { t, bitcast(a) } -> one 8B uniform load per edge.
// ---------------------------------------------------------------------------
__global__ __launch_bounds__(256)
void hist_k(const int* __restrict__ all_h, int* __restrict__ cnt) {
    int e = blockIdx.x * 256 + threadIdx.x;
    if (e < N_EDGES) atomicAdd(&cnt[all_h[e]], 1);
}

__global__ __launch_bounds__(256)
void scan_k(const int* __restrict__ cnt, int* __restrict__ offsets) {
    constexpr int CHUNK = (N_NODES + 255) / 256;   // 586
    __shared__ int partial[256];
    __shared__ int excl[256];
    int tid = threadIdx.x;
    int begin = tid * CHUNK;
    int end = begin + CHUNK; if (end > N_NODES) end = N_NODES;
    int s = 0;
    for (int i = begin; i < end; ++i) s += cnt[i];
    partial[tid] = s;
    __syncthreads();
    if (tid == 0) {
        int run = 0;
        for (int i = 0; i < 256; ++i) { excl[i] = run; run += partial[i]; }
    }
    __syncthreads();
    int run = excl[tid];
    for (int i = begin; i < end; ++i) { offsets[i] = run; run += cnt[i]; }
    if (end == N_NODES && begin < N_NODES) offsets[N_NODES] = run;
}

__global__ __launch_bounds__(256)
void fill_k(const int* __restrict__ all_h, const int* __restrict__ all_t,
            const float* __restrict__ A,
            const int* __restrict__ offsets, int* __restrict__ cursor,
            int2* __restrict__ edge_ta) {
    int e = blockIdx.x * 256 + threadIdx.x;
    if (e >= N_EDGES) return;
    int h = all_h[e];
    int p = offsets[h] + atomicAdd(&cursor[h], 1);
    edge_ta[p] = make_int2(all_t[e], __float_as_int(A[e]));
}

// ---------------------------------------------------------------------------
// side_k: pure CSR segment-sum. One wave per node h:
//   side[h] = sum_e A_e * ego[t_e]       (4x unrolled for MLP, no LDS)
// ---------------------------------------------------------------------------
template<int DIN, bool CONCAT>
__global__ __launch_bounds__(256)
void side_k(const int* __restrict__ offsets,
            const int2* __restrict__ edge_ta,
            const float* __restrict__ ego_in,
            const float* __restrict__ user_emb, const float* __restrict__ ent_emb,
            float* __restrict__ side) {
    int w = threadIdx.x >> 6;
    int lane = threadIdx.x & 63;
    int h = blockIdx.x * 4 + w;

    int e0 = offsets[h], e1 = offsets[h + 1];

    if (DIN == 64) {
        float acc = 0.f;
        int e = e0;
        #define ROW64(t) (CONCAT ? (((t) < N_USERS) ? (user_emb + (size_t)(t) * 64) \
                                                    : (ent_emb + (size_t)((t) - N_USERS) * 64)) \
                                 : (ego_in + (size_t)(t) * 64))
        for (; e + 4 <= e1; e += 4) {
            int2 p0 = edge_ta[e + 0];
            int2 p1 = edge_ta[e + 1];
            int2 p2 = edge_ta[e + 2];
            int2 p3 = edge_ta[e + 3];
            const float* r0 = ROW64(p0.x);
            const float* r1 = ROW64(p1.x);
            const float* r2 = ROW64(p2.x);
            const float* r3 = ROW64(p3.x);
            float x0 = r0[lane], x1 = r1[lane], x2 = r2[lane], x3 = r3[lane];
            acc = fmaf(__int_as_float(p0.y), x0, acc);
            acc = fmaf(__int_as_float(p1.y), x1, acc);
            acc = fmaf(__int_as_float(p2.y), x2, acc);
            acc = fmaf(__int_as_float(p3.y), x3, acc);
        }
        for (; e < e1; ++e) {
            int2 p = edge_ta[e];
            acc = fmaf(__int_as_float(p.y), ROW64(p.x)[lane], acc);
        }
        #undef ROW64
        side[(size_t)h * 64 + lane] = acc;
    } else {  // DIN == 32: two half-waves split the edges, combine via shfl
        int col = lane & 31;
        int half = lane >> 5;
        float acc = 0.f;
        int e = e0 + half;
        for (; e + 6 < e1; e += 8) {
            int2 p0 = edge_ta[e + 0];
            int2 p1 = edge_ta[e + 2];
            int2 p2 = edge_ta[e + 4];
            int2 p3 = edge_ta[e + 6];
            float x0 = ego_in[(size_t)p0.x * 32 + col];
            float x1 = ego_in[(size_t)p1.x * 32 + col];
            float x2 = ego_in[(size_t)p2.x * 32 + col];
            float x3 = ego_in[(size_t)p3.x * 32 + col];
            acc = fmaf(__int_as_float(p0.y), x0, acc);
            acc = fmaf(__int_as_float(p1.y), x1, acc);
            acc = fmaf(__int_as_float(p2.y), x2, acc);
            acc = fmaf(__int_as_float(p3.y), x3, acc);
        }
        for (; e < e1; e += 2) {
            int2 p = edge_ta[e];
            acc = fmaf(__int_as_float(p.y), ego_in[(size_t)p.x * 32 + col], acc);
        }
        acc += __shfl_xor(acc, 32, 64);
        if (lane < 32) side[(size_t)h * 32 + lane] = acc;
    }
}

// ---------------------------------------------------------------------------
// transform_k: tiled vector GEMM over node rows.
//   su = ego+side, sv = ego*side  (computed during staging)
//   out = leaky(su@Wgc + bgc) + leaky(sv@Wbi + bbi)
// W staged once per block in LDS; su/sv tile in LDS (stride DIN+4 to break
// bank alignment); per-thread micro-tile RT rows x 8 cols, float4 LDS reads.
// ---------------------------------------------------------------------------
template<int DIN, int DOUT, int TILE_ROWS, bool CONCAT>
__global__ __launch_bounds__(256)
void transform_k(const float* __restrict__ ego_in,
                 const float* __restrict__ user_emb, const float* __restrict__ ent_emb,
                 const float* __restrict__ side,
                 const float* __restrict__ Wgc, const float* __restrict__ bgc,
                 const float* __restrict__ Wbi, const float* __restrict__ bbi,
                 float* __restrict__ ego_out) {
    constexpr int NG = DOUT / 8;          // col groups
    constexpr int RG = 256 / NG;          // row groups
    constexpr int RT = TILE_ROWS / RG;    // rows per thread
    constexpr int STRIDE = DIN + 4;       // LDS row stride (floats)
    constexpr int KC = DIN / 4;           // float4 chunks per row

    __shared__ float sWgc[DIN * DOUT], sWbi[DIN * DOUT];
    __shared__ float sU[TILE_ROWS * STRIDE], sV[TILE_ROWS * STRIDE];

    int t = threadIdx.x;

    // stage W (each element once per block)
    for (int i = t * 4; i < DIN * DOUT; i += 1024) {
        *(float4*)&sWgc[i] = *(const float4*)&Wgc[i];
        *(float4*)&sWbi[i] = *(const float4*)&Wbi[i];
    }

    // stage su/sv tile
    int base = blockIdx.x * TILE_ROWS;
    for (int f = t; f < TILE_ROWS * KC; f += 256) {
        int row = f / KC, kc = f % KC;
        int n = base + row;
        int nc = n < N_NODES ? n : N_NODES - 1;      // clamp loads, guard stores
        const float* erow;
        if (CONCAT) {
            erow = (nc < N_USERS) ? user_emb + (size_t)nc * 64
                                  : ent_emb + (size_t)(nc - N_USERS) * 64;
        } else {
            erow = ego_in + (size_t)nc * DIN;
        }
        float4 e4 = ((const float4*)erow)[kc];
        float4 s4 = ((const float4*)(side + (size_t)nc * DIN))[kc];
        float4 u4, v4;
        u4.x = e4.x + s4.x; u4.y = e4.y + s4.y; u4.z = e4.z + s4.z; u4.w = e4.w + s4.w;
        v4.x = e4.x * s4.x; v4.y = e4.y * s4.y; v4.z = e4.z * s4.z; v4.w = e4.w * s4.w;
        *(float4*)&sU[row * STRIDE + kc * 4] = u4;
        *(float4*)&sV[row * STRIDE + kc * 4] = v4;
    }
    __syncthreads();

    int cg = t % NG, rg = t / NG;
    int c0 = cg * 8;
    int r0 = rg * RT;

    float accg[RT][8], accb[RT][8];
    #pragma unroll
    for (int r = 0; r < RT; ++r)
        #pragma unroll
        for (int j = 0; j < 8; ++j) { accg[r][j] = 0.f; accb[r][j] = 0.f; }

    for (int k = 0; k < DIN; k += 4) {
        float4 u4[RT], v4[RT];
        #pragma unroll
        for (int r = 0; r < RT; ++r) {
            u4[r] = *(const float4*)&sU[(r0 + r) * STRIDE + k];
            v4[r] = *(const float4*)&sV[(r0 + r) * STRIDE + k];
        }
        #pragma unroll
        for (int kk = 0; kk < 4; ++kk) {
            float4 wg0 = *(const float4*)&sWgc[(k + kk) * DOUT + c0];
            float4 wg1 = *(const float4*)&sWgc[(k + kk) * DOUT + c0 + 4];
            float4 wb0 = *(const float4*)&sWbi[(k + kk) * DOUT + c0];
            float4 wb1 = *(const float4*)&sWbi[(k + kk) * DOUT + c0 + 4];
            #pragma unroll
            for (int r = 0; r < RT; ++r) {
                float u = ((const float*)&u4[r])[kk];
                float v = ((const float*)&v4[r])[kk];
                accg[r][0] = fmaf(u, wg0.x, accg[r][0]);
                accg[r][1] = fmaf(u, wg0.y, accg[r][1]);
                accg[r][2] = fmaf(u, wg0.z, accg[r][2]);
                accg[r][3] = fmaf(u, wg0.w, accg[r][3]);
                accg[r][4] = fmaf(u, wg1.x, accg[r][4]);
                accg[r][5] = fmaf(u, wg1.y, accg[r][5]);
                accg[r][6] = fmaf(u, wg1.z, accg[r][6]);
                accg[r][7] = fmaf(u, wg1.w, accg[r][7]);
                accb[r][0] = fmaf(v, wb0.x, accb[r][0]);
                accb[r][1] = fmaf(v, wb0.y, accb[r][1]);
                accb[r][2] = fmaf(v, wb0.z, accb[r][2]);
                accb[r][3] = fmaf(v, wb0.w, accb[r][3]);
                accb[r][4] = fmaf(v, wb1.x, accb[r][4]);
                accb[r][5] = fmaf(v, wb1.y, accb[r][5]);
                accb[r][6] = fmaf(v, wb1.z, accb[r][6]);
                accb[r][7] = fmaf(v, wb1.w, accb[r][7]);
            }
        }
    }

    // epilogue: bias + leaky + sum, guarded store
    float4 bg0 = *(const float4*)&bgc[c0];
    float4 bg1 = *(const float4*)&bgc[c0 + 4];
    float4 bb0 = *(const float4*)&bbi[c0];
    float4 bb1 = *(const float4*)&bbi[c0 + 4];
    float bg[8] = {bg0.x, bg0.y, bg0.z, bg0.w, bg1.x, bg1.y, bg1.z, bg1.w};
    float bb[8] = {bb0.x, bb0.y, bb0.z, bb0.w, bb1.x, bb1.y, bb1.z, bb1.w};

    #pragma unroll
    for (int r = 0; r < RT; ++r) {
        int n = base + r0 + r;
        if (n < N_NODES) {
            float o[8];
            #pragma unroll
            for (int j = 0; j < 8; ++j) {
                float g = accg[r][j] + bg[j];
                float b = accb[r][j] + bb[j];
                g = g > 0.f ? g : SLOPE * g;
                b = b > 0.f ? b : SLOPE * b;
                o[j] = g + b;
            }
            float* dst = ego_out + (size_t)n * DOUT + c0;
            *(float4*)dst       = make_float4(o[0], o[1], o[2], o[3]);
            *(float4*)(dst + 4) = make_float4(o[4], o[5], o[6], o[7]);
        }
    }
}

// ---------------------------------------------------------------------------
// Gather: out rows = [ego0(64) | norm(ego1)(64) | norm(ego2)(32) | norm(ego3)(16)]
// ---------------------------------------------------------------------------
__global__ __launch_bounds__(64)
void gather_k(const int* __restrict__ users, const int* __restrict__ pos,
              const int* __restrict__ neg,
              const float* __restrict__ user_emb, const float* __restrict__ ent_emb,
              const float* __restrict__ ego1, const float* __restrict__ ego2,
              const float* __restrict__ ego3,
              float* __restrict__ out) {
    int r = blockIdx.x;               // 0 .. 3*BATCH-1
    int lane = threadIdx.x;           // 0 .. 63
    int which = r / BATCH;
    int i = r - which * BATCH;
    int node;
    if (which == 0)      node = users[i];
    else if (which == 1) node = N_USERS + pos[i];
    else                 node = N_USERS + neg[i];

    float* o = out + (size_t)r * 176;

    float x0 = (node < N_USERS) ? user_emb[(size_t)node * 64 + lane]
                                : ent_emb[(size_t)(node - N_USERS) * 64 + lane];
    o[lane] = x0;

    float x1 = ego1[(size_t)node * 64 + lane];
    float ss = x1 * x1;
    #pragma unroll
    for (int off = 32; off > 0; off >>= 1) ss += __shfl_xor(ss, off, 64);
    o[64 + lane] = x1 / fmaxf(sqrtf(ss), EPSF);

    float x2 = (lane < 32) ? ego2[(size_t)node * 32 + lane] : 0.f;
    float ss2 = x2 * x2;
    #pragma unroll
    for (int off = 32; off > 0; off >>= 1) ss2 += __shfl_xor(ss2, off, 64);
    if (lane < 32) o[128 + lane] = x2 / fmaxf(sqrtf(ss2), EPSF);

    float x3 = (lane < 16) ? ego3[(size_t)node * 16 + lane] : 0.f;
    float ss3 = x3 * x3;
    #pragma unroll
    for (int off = 32; off > 0; off >>= 1) ss3 += __shfl_xor(ss3, off, 64);
    if (lane < 16) o[160 + lane] = x3 / fmaxf(sqrtf(ss3), EPSF);
}

// ---------------------------------------------------------------------------
extern "C" void kernel_launch(void* const* d_in, const int* in_sizes, int n_in,
                              void* d_out, int out_size, void* d_ws, size_t ws_size,
                              hipStream_t stream) {
    const int*   users    = (const int*)d_in[0];
    const int*   pos      = (const int*)d_in[1];
    const int*   neg      = (const int*)d_in[2];
    const int*   all_h    = (const int*)d_in[3];
    const int*   all_t    = (const int*)d_in[4];
    const float* A        = (const float*)d_in[5];
    const float* user_emb = (const float*)d_in[6];
    const float* ent_emb  = (const float*)d_in[7];
    const float* Wgc0 = (const float*)d_in[8];
    const float* bgc0 = (const float*)d_in[9];
    const float* Wbi0 = (const float*)d_in[10];
    const float* bbi0 = (const float*)d_in[11];
    const float* Wgc1 = (const float*)d_in[12];
    const float* bgc1 = (const float*)d_in[13];
    const float* Wbi1 = (const float*)d_in[14];
    const float* bbi1 = (const float*)d_in[15];
    const float* Wgc2 = (const float*)d_in[16];
    const float* bgc2 = (const float*)d_in[17];
    const float* Wbi2 = (const float*)d_in[18];
    const float* bbi2 = (const float*)d_in[19];

    // ---- workspace carve-up (256B-aligned chunks) ----
    char* p = (char*)d_ws;
    int*   cnt     = (int*)p;    p += ((size_t)N_NODES * 4 + 255) & ~255ull;   // counts, then cursor
    int*   offsets = (int*)p;    p += ((size_t)(N_NODES + 1) * 4 + 255) & ~255ull;
    int2*  edge_ta = (int2*)p;   p += ((size_t)N_EDGES * 8 + 255) & ~255ull;
    float* side    = (float*)p;  p += ((size_t)N_NODES * 64 * 4 + 255) & ~255ull;  // reused per layer
    float* ego1    = (float*)p;  p += ((size_t)N_NODES * 64 * 4 + 255) & ~255ull;
    float* ego2    = (float*)p;  p += ((size_t)N_NODES * 32 * 4 + 255) & ~255ull;
    float* ego3    = (float*)p;  p += ((size_t)N_NODES * 16 * 4 + 255) & ~255ull;
    float* out     = (float*)d_out;

    const int edgeBlocks = (N_EDGES + 255) / 256;
    const int nodeBlocks = N_NODES / 4;   // 150000 % 4 == 0

    // ---- CSR build (once; all_h shared across layers) ----
    (void)hipMemsetAsync(cnt, 0, (size_t)N_NODES * 4, stream);
    hist_k<<<edgeBlocks, 256, 0, stream>>>(all_h, cnt);
    scan_k<<<1, 256, 0, stream>>>(cnt, offsets);
    (void)hipMemsetAsync(cnt, 0, (size_t)N_NODES * 4, stream);   // now cursor
    fill_k<<<edgeBlocks, 256, 0, stream>>>(all_h, all_t, A, offsets, cnt, edge_ta);

    // ---- layer 0: 64 -> 64 ----
    side_k<64, true><<<nodeBlocks, 256, 0, stream>>>(
        offsets, edge_ta, nullptr, user_emb, ent_emb, side);
    transform_k<64, 64, 64, true><<<(N_NODES + 63) / 64, 256, 0, stream>>>(
        nullptr, user_emb, ent_emb, side, Wgc0, bgc0, Wbi0, bbi0, ego1);

    // ---- layer 1: 64 -> 32 ----
    side_k<64, false><<<nodeBlocks, 256, 0, stream>>>(
        offsets, edge_ta, ego1, nullptr, nullptr, side);
    transform_k<64, 32, 64, false><<<(N_NODES + 63) / 64, 256, 0, stream>>>(
        ego1, nullptr, nullptr, side, Wgc1, bgc1, Wbi1, bbi1, ego2);

    // ---- layer 2: 32 -> 16 ----
    side_k<32, false><<<nodeBlocks, 256, 0, stream>>>(
        offsets, edge_ta, ego2, nullptr, nullptr, side);
    transform_k<32, 16, 128, false><<<(N_NODES + 127) / 128, 256, 0, stream>>>(
        ego2, nullptr, nullptr, side, Wgc2, bgc2, Wbi2, bbi2, ego3);

    // ---- final gather + lazy normalization ----
    gather_k<<<3 * BATCH, 64, 0, stream>>>(
        users, pos, neg, user_emb, ent_emb, ego1, ego2, ego3, out);
}

// Round 6
// 852.814 us; speedup vs baseline: 7.9821x; 1.2719x over previous
//
#include <hip/hip_runtime.h>
#include <math.h>

#define N_USERS    50000
#define N_ENTITIES 100000
#define N_NODES    150000
#define N_EDGES    3000000
#define BATCH      8192
#define SLOPE      0.2f
#define EPSF       1e-12f
#define NB_SCAN    ((N_NODES + 255) / 256)   // 586

// ---------------------------------------------------------------------------
// CSR build: histogram -> hierarchical scan -> fill (sorted-by-h records).
// Edge record: int2 { t, bitcast(a) } -> one 8B uniform load per edge.
// ---------------------------------------------------------------------------
__global__ __launch_bounds__(256)
void hist_k(const int* __restrict__ all_h, int* __restrict__ cnt) {
    int e = blockIdx.x * 256 + threadIdx.x;
    if (e < N_EDGES) atomicAdd(&cnt[all_h[e]], 1);
}

// stage 1: per-block sums of cnt (256 elements per block)
__global__ __launch_bounds__(256)
void scan_bsum_k(const int* __restrict__ cnt, int* __restrict__ bsum) {
    int i = blockIdx.x * 256 + threadIdx.x;
    int v = (i < N_NODES) ? cnt[i] : 0;
    #pragma unroll
    for (int off = 32; off > 0; off >>= 1) v += __shfl_down(v, off, 64);
    __shared__ int ws[4];
    if ((threadIdx.x & 63) == 0) ws[threadIdx.x >> 6] = v;
    __syncthreads();
    if (threadIdx.x == 0) bsum[blockIdx.x] = ws[0] + ws[1] + ws[2] + ws[3];
}

// stage 2: single-block exclusive scan of NB_SCAN block sums -> boff,
// writes offsets[N_NODES] = grand total.
__global__ __launch_bounds__(256)
void scan_boff_k(const int* __restrict__ bsum, int* __restrict__ boff,
                 int* __restrict__ offsets) {
    __shared__ int s[256];
    int t = threadIdx.x;
    int carry = 0;
    for (int c = 0; c < (NB_SCAN + 255) / 256; ++c) {
        int idx = c * 256 + t;
        int v = (idx < NB_SCAN) ? bsum[idx] : 0;
        s[t] = v;
        __syncthreads();
        #pragma unroll
        for (int off = 1; off < 256; off <<= 1) {
            int x = (t >= off) ? s[t - off] : 0;
            __syncthreads();
            s[t] += x;
            __syncthreads();
        }
        if (idx < NB_SCAN) boff[idx] = carry + s[t] - v;   // exclusive
        carry += s[255];
        __syncthreads();
    }
    if (t == 0) offsets[N_NODES] = carry;
}

// stage 3: per-block local exclusive scan + block offset -> offsets[i]
__global__ __launch_bounds__(256)
void scan_out_k(const int* __restrict__ cnt, const int* __restrict__ boff,
                int* __restrict__ offsets) {
    __shared__ int s[256];
    int t = threadIdx.x;
    int i = blockIdx.x * 256 + t;
    int v = (i < N_NODES) ? cnt[i] : 0;
    s[t] = v;
    __syncthreads();
    #pragma unroll
    for (int off = 1; off < 256; off <<= 1) {
        int x = (t >= off) ? s[t - off] : 0;
        __syncthreads();
        s[t] += x;
        __syncthreads();
    }
    if (i < N_NODES) offsets[i] = boff[blockIdx.x] + s[t] - v;
}

__global__ __launch_bounds__(256)
void fill_k(const int* __restrict__ all_h, const int* __restrict__ all_t,
            const float* __restrict__ A,
            const int* __restrict__ offsets, int* __restrict__ cursor,
            int2* __restrict__ edge_ta) {
    int e = blockIdx.x * 256 + threadIdx.x;
    if (e >= N_EDGES) return;
    int h = all_h[e];
    int p = offsets[h] + atomicAdd(&cursor[h], 1);
    edge_ta[p] = make_int2(all_t[e], __float_as_int(A[e]));
}

// ---------------------------------------------------------------------------
// side_k: pure CSR segment-sum. One wave per node h:
//   side[h] = sum_e A_e * ego[t_e]       (8x unrolled for MLP, no LDS)
// ---------------------------------------------------------------------------
template<int DIN, bool CONCAT>
__global__ __launch_bounds__(256)
void side_k(const int* __restrict__ offsets,
            const int2* __restrict__ edge_ta,
            const float* __restrict__ ego_in,
            const float* __restrict__ user_emb, const float* __restrict__ ent_emb,
            float* __restrict__ side) {
    int w = threadIdx.x >> 6;
    int lane = threadIdx.x & 63;
    int h = blockIdx.x * 4 + w;

    int e0 = offsets[h], e1 = offsets[h + 1];

    if (DIN == 64) {
        float acc = 0.f;
        int e = e0;
        #define ROW64(t) (CONCAT ? (((t) < N_USERS) ? (user_emb + (size_t)(t) * 64) \
                                                    : (ent_emb + (size_t)((t) - N_USERS) * 64)) \
                                 : (ego_in + (size_t)(t) * 64))
        for (; e + 8 <= e1; e += 8) {
            int2 p0 = edge_ta[e + 0];
            int2 p1 = edge_ta[e + 1];
            int2 p2 = edge_ta[e + 2];
            int2 p3 = edge_ta[e + 3];
            int2 p4 = edge_ta[e + 4];
            int2 p5 = edge_ta[e + 5];
            int2 p6 = edge_ta[e + 6];
            int2 p7 = edge_ta[e + 7];
            float x0 = ROW64(p0.x)[lane];
            float x1 = ROW64(p1.x)[lane];
            float x2 = ROW64(p2.x)[lane];
            float x3 = ROW64(p3.x)[lane];
            float x4 = ROW64(p4.x)[lane];
            float x5 = ROW64(p5.x)[lane];
            float x6 = ROW64(p6.x)[lane];
            float x7 = ROW64(p7.x)[lane];
            acc = fmaf(__int_as_float(p0.y), x0, acc);
            acc = fmaf(__int_as_float(p1.y), x1, acc);
            acc = fmaf(__int_as_float(p2.y), x2, acc);
            acc = fmaf(__int_as_float(p3.y), x3, acc);
            acc = fmaf(__int_as_float(p4.y), x4, acc);
            acc = fmaf(__int_as_float(p5.y), x5, acc);
            acc = fmaf(__int_as_float(p6.y), x6, acc);
            acc = fmaf(__int_as_float(p7.y), x7, acc);
        }
        for (; e < e1; ++e) {
            int2 p = edge_ta[e];
            acc = fmaf(__int_as_float(p.y), ROW64(p.x)[lane], acc);
        }
        #undef ROW64
        side[(size_t)h * 64 + lane] = acc;
    } else {  // DIN == 32: two half-waves split the edges, combine via shfl
        int col = lane & 31;
        int half = lane >> 5;
        float acc = 0.f;
        int e = e0 + half;
        for (; e + 6 < e1; e += 8) {
            int2 p0 = edge_ta[e + 0];
            int2 p1 = edge_ta[e + 2];
            int2 p2 = edge_ta[e + 4];
            int2 p3 = edge_ta[e + 6];
            float x0 = ego_in[(size_t)p0.x * 32 + col];
            float x1 = ego_in[(size_t)p1.x * 32 + col];
            float x2 = ego_in[(size_t)p2.x * 32 + col];
            float x3 = ego_in[(size_t)p3.x * 32 + col];
            acc = fmaf(__int_as_float(p0.y), x0, acc);
            acc = fmaf(__int_as_float(p1.y), x1, acc);
            acc = fmaf(__int_as_float(p2.y), x2, acc);
            acc = fmaf(__int_as_float(p3.y), x3, acc);
        }
        for (; e < e1; e += 2) {
            int2 p = edge_ta[e];
            acc = fmaf(__int_as_float(p.y), ego_in[(size_t)p.x * 32 + col], acc);
        }
        acc += __shfl_xor(acc, 32, 64);
        if (lane < 32) side[(size_t)h * 32 + lane] = acc;
    }
}

// ---------------------------------------------------------------------------
// transform_k: tiled vector GEMM over node rows.
//   su = ego+side, sv = ego*side  (computed during staging)
//   out = leaky(su@Wgc + bgc) + leaky(sv@Wbi + bbi)
// ---------------------------------------------------------------------------
template<int DIN, int DOUT, int TILE_ROWS, bool CONCAT>
__global__ __launch_bounds__(256)
void transform_k(const float* __restrict__ ego_in,
                 const float* __restrict__ user_emb, const float* __restrict__ ent_emb,
                 const float* __restrict__ side,
                 const float* __restrict__ Wgc, const float* __restrict__ bgc,
                 const float* __restrict__ Wbi, const float* __restrict__ bbi,
                 float* __restrict__ ego_out) {
    constexpr int NG = DOUT / 8;          // col groups
    constexpr int RG = 256 / NG;          // row groups
    constexpr int RT = TILE_ROWS / RG;    // rows per thread
    constexpr int STRIDE = DIN + 4;       // LDS row stride (floats)
    constexpr int KC = DIN / 4;           // float4 chunks per row

    __shared__ float sWgc[DIN * DOUT], sWbi[DIN * DOUT];
    __shared__ float sU[TILE_ROWS * STRIDE], sV[TILE_ROWS * STRIDE];

    int t = threadIdx.x;

    for (int i = t * 4; i < DIN * DOUT; i += 1024) {
        *(float4*)&sWgc[i] = *(const float4*)&Wgc[i];
        *(float4*)&sWbi[i] = *(const float4*)&Wbi[i];
    }

    int base = blockIdx.x * TILE_ROWS;
    for (int f = t; f < TILE_ROWS * KC; f += 256) {
        int row = f / KC, kc = f % KC;
        int n = base + row;
        int nc = n < N_NODES ? n : N_NODES - 1;
        const float* erow;
        if (CONCAT) {
            erow = (nc < N_USERS) ? user_emb + (size_t)nc * 64
                                  : ent_emb + (size_t)(nc - N_USERS) * 64;
        } else {
            erow = ego_in + (size_t)nc * DIN;
        }
        float4 e4 = ((const float4*)erow)[kc];
        float4 s4 = ((const float4*)(side + (size_t)nc * DIN))[kc];
        float4 u4, v4;
        u4.x = e4.x + s4.x; u4.y = e4.y + s4.y; u4.z = e4.z + s4.z; u4.w = e4.w + s4.w;
        v4.x = e4.x * s4.x; v4.y = e4.y * s4.y; v4.z = e4.z * s4.z; v4.w = e4.w * s4.w;
        *(float4*)&sU[row * STRIDE + kc * 4] = u4;
        *(float4*)&sV[row * STRIDE + kc * 4] = v4;
    }
    __syncthreads();

    int cg = t % NG, rg = t / NG;
    int c0 = cg * 8;
    int r0 = rg * RT;

    float accg[RT][8], accb[RT][8];
    #pragma unroll
    for (int r = 0; r < RT; ++r)
        #pragma unroll
        for (int j = 0; j < 8; ++j) { accg[r][j] = 0.f; accb[r][j] = 0.f; }

    for (int k = 0; k < DIN; k += 4) {
        float4 u4[RT], v4[RT];
        #pragma unroll
        for (int r = 0; r < RT; ++r) {
            u4[r] = *(const float4*)&sU[(r0 + r) * STRIDE + k];
            v4[r] = *(const float4*)&sV[(r0 + r) * STRIDE + k];
        }
        #pragma unroll
        for (int kk = 0; kk < 4; ++kk) {
            float4 wg0 = *(const float4*)&sWgc[(k + kk) * DOUT + c0];
            float4 wg1 = *(const float4*)&sWgc[(k + kk) * DOUT + c0 + 4];
            float4 wb0 = *(const float4*)&sWbi[(k + kk) * DOUT + c0];
            float4 wb1 = *(const float4*)&sWbi[(k + kk) * DOUT + c0 + 4];
            #pragma unroll
            for (int r = 0; r < RT; ++r) {
                float u = ((const float*)&u4[r])[kk];
                float v = ((const float*)&v4[r])[kk];
                accg[r][0] = fmaf(u, wg0.x, accg[r][0]);
                accg[r][1] = fmaf(u, wg0.y, accg[r][1]);
                accg[r][2] = fmaf(u, wg0.z, accg[r][2]);
                accg[r][3] = fmaf(u, wg0.w, accg[r][3]);
                accg[r][4] = fmaf(u, wg1.x, accg[r][4]);
                accg[r][5] = fmaf(u, wg1.y, accg[r][5]);
                accg[r][6] = fmaf(u, wg1.z, accg[r][6]);
                accg[r][7] = fmaf(u, wg1.w, accg[r][7]);
                accb[r][0] = fmaf(v, wb0.x, accb[r][0]);
                accb[r][1] = fmaf(v, wb0.y, accb[r][1]);
                accb[r][2] = fmaf(v, wb0.z, accb[r][2]);
                accb[r][3] = fmaf(v, wb0.w, accb[r][3]);
                accb[r][4] = fmaf(v, wb1.x, accb[r][4]);
                accb[r][5] = fmaf(v, wb1.y, accb[r][5]);
                accb[r][6] = fmaf(v, wb1.z, accb[r][6]);
                accb[r][7] = fmaf(v, wb1.w, accb[r][7]);
            }
        }
    }

    float4 bg0 = *(const float4*)&bgc[c0];
    float4 bg1 = *(const float4*)&bgc[c0 + 4];
    float4 bb0 = *(const float4*)&bbi[c0];
    float4 bb1 = *(const float4*)&bbi[c0 + 4];
    float bg[8] = {bg0.x, bg0.y, bg0.z, bg0.w, bg1.x, bg1.y, bg1.z, bg1.w};
    float bb[8] = {bb0.x, bb0.y, bb0.z, bb0.w, bb1.x, bb1.y, bb1.z, bb1.w};

    #pragma unroll
    for (int r = 0; r < RT; ++r) {
        int n = base + r0 + r;
        if (n < N_NODES) {
            float o[8];
            #pragma unroll
            for (int j = 0; j < 8; ++j) {
                float g = accg[r][j] + bg[j];
                float b = accb[r][j] + bb[j];
                g = g > 0.f ? g : SLOPE * g;
                b = b > 0.f ? b : SLOPE * b;
                o[j] = g + b;
            }
            float* dst = ego_out + (size_t)n * DOUT + c0;
            *(float4*)dst       = make_float4(o[0], o[1], o[2], o[3]);
            *(float4*)(dst + 4) = make_float4(o[4], o[5], o[6], o[7]);
        }
    }
}

// ---------------------------------------------------------------------------
// Gather: out rows = [ego0(64) | norm(ego1)(64) | norm(ego2)(32) | norm(ego3)(16)]
// ---------------------------------------------------------------------------
__global__ __launch_bounds__(64)
void gather_k(const int* __restrict__ users, const int* __restrict__ pos,
              const int* __restrict__ neg,
              const float* __restrict__ user_emb, const float* __restrict__ ent_emb,
              const float* __restrict__ ego1, const float* __restrict__ ego2,
              const float* __restrict__ ego3,
              float* __restrict__ out) {
    int r = blockIdx.x;               // 0 .. 3*BATCH-1
    int lane = threadIdx.x;           // 0 .. 63
    int which = r / BATCH;
    int i = r - which * BATCH;
    int node;
    if (which == 0)      node = users[i];
    else if (which == 1) node = N_USERS + pos[i];
    else                 node = N_USERS + neg[i];

    float* o = out + (size_t)r * 176;

    float x0 = (node < N_USERS) ? user_emb[(size_t)node * 64 + lane]
                                : ent_emb[(size_t)(node - N_USERS) * 64 + lane];
    o[lane] = x0;

    float x1 = ego1[(size_t)node * 64 + lane];
    float ss = x1 * x1;
    #pragma unroll
    for (int off = 32; off > 0; off >>= 1) ss += __shfl_xor(ss, off, 64);
    o[64 + lane] = x1 / fmaxf(sqrtf(ss), EPSF);

    float x2 = (lane < 32) ? ego2[(size_t)node * 32 + lane] : 0.f;
    float ss2 = x2 * x2;
    #pragma unroll
    for (int off = 32; off > 0; off >>= 1) ss2 += __shfl_xor(ss2, off, 64);
    if (lane < 32) o[128 + lane] = x2 / fmaxf(sqrtf(ss2), EPSF);

    float x3 = (lane < 16) ? ego3[(size_t)node * 16 + lane] : 0.f;
    float ss3 = x3 * x3;
    #pragma unroll
    for (int off = 32; off > 0; off >>= 1) ss3 += __shfl_xor(ss3, off, 64);
    if (lane < 16) o[160 + lane] = x3 / fmaxf(sqrtf(ss3), EPSF);
}

// ---------------------------------------------------------------------------
extern "C" void kernel_launch(void* const* d_in, const int* in_sizes, int n_in,
                              void* d_out, int out_size, void* d_ws, size_t ws_size,
                              hipStream_t stream) {
    const int*   users    = (const int*)d_in[0];
    const int*   pos      = (const int*)d_in[1];
    const int*   neg      = (const int*)d_in[2];
    const int*   all_h    = (const int*)d_in[3];
    const int*   all_t    = (const int*)d_in[4];
    const float* A        = (const float*)d_in[5];
    const float* user_emb = (const float*)d_in[6];
    const float* ent_emb  = (const float*)d_in[7];
    const float* Wgc0 = (const float*)d_in[8];
    const float* bgc0 = (const float*)d_in[9];
    const float* Wbi0 = (const float*)d_in[10];
    const float* bbi0 = (const float*)d_in[11];
    const float* Wgc1 = (const float*)d_in[12];
    const float* bgc1 = (const float*)d_in[13];
    const float* Wbi1 = (const float*)d_in[14];
    const float* bbi1 = (const float*)d_in[15];
    const float* Wgc2 = (const float*)d_in[16];
    const float* bgc2 = (const float*)d_in[17];
    const float* Wbi2 = (const float*)d_in[18];
    const float* bbi2 = (const float*)d_in[19];

    // ---- workspace carve-up (256B-aligned chunks) ----
    char* p = (char*)d_ws;
    int*   cnt     = (int*)p;    p += ((size_t)N_NODES * 4 + 255) & ~255ull;   // counts, then cursor
    int*   offsets = (int*)p;    p += ((size_t)(N_NODES + 1) * 4 + 255) & ~255ull;
    int*   bsum    = (int*)p;    p += ((size_t)NB_SCAN * 4 + 255) & ~255ull;
    int*   boff    = (int*)p;    p += ((size_t)NB_SCAN * 4 + 255) & ~255ull;
    int2*  edge_ta = (int2*)p;   p += ((size_t)N_EDGES * 8 + 255) & ~255ull;
    float* side    = (float*)p;  p += ((size_t)N_NODES * 64 * 4 + 255) & ~255ull;  // reused per layer
    float* ego1    = (float*)p;  p += ((size_t)N_NODES * 64 * 4 + 255) & ~255ull;
    float* ego2    = (float*)p;  p += ((size_t)N_NODES * 32 * 4 + 255) & ~255ull;
    float* ego3    = (float*)p;  p += ((size_t)N_NODES * 16 * 4 + 255) & ~255ull;
    float* out     = (float*)d_out;

    const int edgeBlocks = (N_EDGES + 255) / 256;
    const int nodeBlocks = N_NODES / 4;   // 150000 % 4 == 0

    // ---- CSR build (once; all_h shared across layers) ----
    (void)hipMemsetAsync(cnt, 0, (size_t)N_NODES * 4, stream);
    hist_k<<<edgeBlocks, 256, 0, stream>>>(all_h, cnt);
    scan_bsum_k<<<NB_SCAN, 256, 0, stream>>>(cnt, bsum);
    scan_boff_k<<<1, 256, 0, stream>>>(bsum, boff, offsets);
    scan_out_k<<<NB_SCAN, 256, 0, stream>>>(cnt, boff, offsets);
    (void)hipMemsetAsync(cnt, 0, (size_t)N_NODES * 4, stream);   // now cursor
    fill_k<<<edgeBlocks, 256, 0, stream>>>(all_h, all_t, A, offsets, cnt, edge_ta);

    // ---- layer 0: 64 -> 64 ----
    side_k<64, true><<<nodeBlocks, 256, 0, stream>>>(
        offsets, edge_ta, nullptr, user_emb, ent_emb, side);
    transform_k<64, 64, 64, true><<<(N_NODES + 63) / 64, 256, 0, stream>>>(
        nullptr, user_emb, ent_emb, side, Wgc0, bgc0, Wbi0, bbi0, ego1);

    // ---- layer 1: 64 -> 32 ----
    side_k<64, false><<<nodeBlocks, 256, 0, stream>>>(
        offsets, edge_ta, ego1, nullptr, nullptr, side);
    transform_k<64, 32, 64, false><<<(N_NODES + 63) / 64, 256, 0, stream>>>(
        ego1, nullptr, nullptr, side, Wgc1, bgc1, Wbi1, bbi1, ego2);

    // ---- layer 2: 32 -> 16 ----
    side_k<32, false><<<nodeBlocks, 256, 0, stream>>>(
        offsets, edge_ta, ego2, nullptr, nullptr, side);
    transform_k<32, 16, 128, false><<<(N_NODES + 127) / 128, 256, 0, stream>>>(
        ego2, nullptr, nullptr, side, Wgc2, bgc2, Wbi2, bbi2, ego3);

    // ---- final gather + lazy normalization ----
    gather_k<<<3 * BATCH, 64, 0, stream>>>(
        users, pos, neg, user_emb, ent_emb, ego1, ego2, ego3, out);
}